// Round 6
// baseline (457.308 us; speedup 1.0000x reference)
//
#include <hip/hip_runtime.h>

#define T_STEPS 256
#define BATCH   128
#define FEAT    1536            // DH * L = 512 * 3
#define NPAIRS  (T_STEPS * BATCH)

typedef float vf2 __attribute__((ext_vector_type(2)));   // nontemporal-storable
typedef float vf4 __attribute__((ext_vector_type(4)));

// ---------------------------------------------------------------------------
// DPP full-wave (64-lane) sum. Result valid in lane 63. All VALU-pipe.
// ---------------------------------------------------------------------------
template <int CTRL, int RMASK>
__device__ __forceinline__ float dpp_add_step(float v) {
    int m = __builtin_amdgcn_update_dpp(0, __float_as_int(v), CTRL, RMASK, 0xF, true);
    return v + __int_as_float(m);
}

__device__ __forceinline__ float wave_reduce63(float v) {
    v = dpp_add_step<0x111, 0xF>(v);   // row_shr:1
    v = dpp_add_step<0x112, 0xF>(v);   // row_shr:2
    v = dpp_add_step<0x114, 0xF>(v);   // row_shr:4
    v = dpp_add_step<0x118, 0xF>(v);   // row_shr:8  -> lanes 15/31/47/63
    v = dpp_add_step<0x142, 0xA>(v);   // row_bcast:15 into rows 1,3
    v = dpp_add_step<0x143, 0xC>(v);   // row_bcast:31 into rows 2,3
    return v;
}

// 1 - sigmoid(x) = 1/(1 + e^x); inf-safe without clamps (rcp(inf)=0).
__device__ __forceinline__ float one_minus_sig(float x) {
    float e = __builtin_amdgcn_exp2f(x * 1.4426950408889634f);
    return __builtin_amdgcn_rcpf(1.0f + e);
}

// tanh(x) = 1 - 2/(1 + e^{2x}); saturates correctly at +/-inf, no clamps.
__device__ __forceinline__ float tanh_fast(float x) {
    float e = __builtin_amdgcn_exp2f(x * 2.8853900817779268f);
    return fmaf(-2.0f, __builtin_amdgcn_rcpf(1.0f + e), 1.0f);
}

// LDS-only barrier: orders ds_write/ds_read across waves WITHOUT draining
// outstanding global stores (keeps HBM store latency off the serial path).
__device__ __forceinline__ void barrier_lds_only() {
    asm volatile("s_waitcnt lgkmcnt(0)\n\ts_barrier" ::: "memory");
}

// ---------------------------------------------------------------------------
// Kernel 1: X[b,t,o] = dot(inputs[t,b,:,:], Wi[o]) + bi[o]
// One block (256 threads) per (t,b) pair. Output transposed (b,t).
// ---------------------------------------------------------------------------
__global__ __launch_bounds__(256) void xdot_kernel(
    const float* __restrict__ x,    // (T*B, 1536)
    const float* __restrict__ Wi,   // (2, 1536)
    const float* __restrict__ bi,   // (2,)
    float* __restrict__ X)          // (B, T) float2
{
    const int p    = blockIdx.x;           // t*BATCH + b
    const int tid  = threadIdx.x;
    const int wid  = tid >> 6;
    const int lane = tid & 63;

    __shared__ float red[8];               // 4 waves x 2 partials

    const float* xp = x + (size_t)p * FEAT;
    const float4 v4 = ((const float4*)xp)[tid];
    const float2 v2 = ((const float2*)(xp + 1024))[tid];

    const float4 w04 = ((const float4*)Wi)[tid];
    const float2 w02 = ((const float2*)(Wi + 1024))[tid];
    const float4 w14 = ((const float4*)(Wi + FEAT))[tid];
    const float2 w12 = ((const float2*)(Wi + FEAT + 1024))[tid];

    float a0 = v4.x * w04.x + v4.y * w04.y + v4.z * w04.z + v4.w * w04.w
             + v2.x * w02.x + v2.y * w02.y;
    float a1 = v4.x * w14.x + v4.y * w14.y + v4.z * w14.z + v4.w * w14.w
             + v2.x * w12.x + v2.y * w12.y;

    a0 = wave_reduce63(a0);
    a1 = wave_reduce63(a1);
    if (lane == 63) {
        red[wid * 2]     = a0;
        red[wid * 2 + 1] = a1;
    }
    __syncthreads();
    if (tid == 0) {
        const float s0 = red[0] + red[2] + red[4] + red[6] + bi[0];
        const float s1 = red[1] + red[3] + red[5] + red[7] + bi[1];
        const int b = p & (BATCH - 1);
        const int t = p >> 7;                    // p / BATCH
        ((float2*)X)[b * T_STEPS + t] = make_float2(s0, s1);
    }
}

// ---------------------------------------------------------------------------
// Kernel 2: sequential scan, one 256-thread block (4 waves) per batch elem.
// R3 structure (best measured) + chain cuts: X[t+1] register-prefetched
// before the barrier, nontemporal fire-and-forget stores, paired dot
// accumulators. One lgkm-only barrier per step, double-buffered red[].
// ---------------------------------------------------------------------------
__global__ __launch_bounds__(256) void scan_kernel(
    const float* __restrict__ h0,
    const float* __restrict__ c0,
    const float* __restrict__ Wr, const float* __restrict__ br,
    const float* __restrict__ Wc, const float* __restrict__ bc,
    const float* __restrict__ X,    // (B, T) float2
    float* __restrict__ outs,       // (T*B, 1536)
    float* __restrict__ hT,         // (B, 1536)
    float* __restrict__ cT)         // (B, 1536)
{
    const int b    = blockIdx.x;
    const int tid  = threadIdx.x;
    const int wid  = tid >> 6;
    const int lane = tid & 63;

    __shared__ float4 red[2][4];        // double-buffered: 4 waves x 4 gates
    __shared__ float2 Xsh[T_STEPS + 1]; // +1 pad so t+1 prefetch never OOB

    Xsh[tid] = ((const float2*)X)[b * T_STEPS + tid];

    const float4 wr0_4 = ((const float4*)Wr)[tid];
    const float4 wr1_4 = ((const float4*)(Wr + FEAT))[tid];
    const float2 wr0_2 = ((const float2*)(Wr + 1024))[tid];
    const float2 wr1_2 = ((const float2*)(Wr + FEAT + 1024))[tid];
    const float4 wc0_4 = ((const float4*)Wc)[tid];
    const float4 wc1_4 = ((const float4*)(Wc + FEAT))[tid];
    const float2 wc0_2 = ((const float2*)(Wc + 1024))[tid];
    const float2 wc1_2 = ((const float2*)(Wc + FEAT + 1024))[tid];
    const float br0 = br[0], br1 = br[1];
    const float bc0 = bc[0], bc1 = bc[1];

    const float* h0b = h0 + (size_t)b * FEAT;
    const float* c0b = c0 + (size_t)b * FEAT;
    float4 h4 = ((const float4*)h0b)[tid];
    float2 h2 = ((const float2*)(h0b + 1024))[tid];
    float4 c4 = ((const float4*)c0b)[tid];
    float2 c2 = ((const float2*)(c0b + 1024))[tid];

    float* op = outs + (size_t)b * FEAT;
    const size_t OSTRIDE = (size_t)BATCH * FEAT;

    __syncthreads();                 // Xsh visible (one-time)
    float2 Xv = Xsh[0];              // step-0 X already in registers

    auto step = [&](float4* buf, int t) {
        // paired accumulators: two shallow independent fma chains per gate
        float aHc0 = h4.x * wr0_4.x + h4.z * wr0_4.z + h2.x * wr0_2.x;
        float aHc1 = h4.y * wr0_4.y + h4.w * wr0_4.w + h2.y * wr0_2.y;
        float aHh0 = h4.x * wr1_4.x + h4.z * wr1_4.z + h2.x * wr1_2.x;
        float aHh1 = h4.y * wr1_4.y + h4.w * wr1_4.w + h2.y * wr1_2.y;
        float aCc0 = c4.x * wc0_4.x + c4.z * wc0_4.z + c2.x * wc0_2.x;
        float aCc1 = c4.y * wc0_4.y + c4.w * wc0_4.w + c2.y * wc0_2.y;
        float aCh0 = c4.x * wc1_4.x + c4.z * wc1_4.z + c2.x * wc1_2.x;
        float aCh1 = c4.y * wc1_4.y + c4.w * wc1_4.w + c2.y * wc1_2.y;

        float pHc = wave_reduce63(aHc0 + aHc1);
        float pHh = wave_reduce63(aHh0 + aHh1);
        float pCc = wave_reduce63(aCc0 + aCc1);
        float pCh = wave_reduce63(aCh0 + aCh1);

        if (lane == 63) {
            buf[wid] = make_float4(pHc, pHh, pCc, pCh);
        }
        const float2 Xnext = Xsh[t + 1];   // prefetch BEFORE barrier: the
                                           // lgkmcnt(0) covers it, so the
                                           // post-barrier chain has no X read
        barrier_lds_only();
        const float4 r0 = buf[0];
        const float4 r1 = buf[1];
        const float4 r2 = buf[2];
        const float4 r3 = buf[3];
        const float Hc = (r0.x + r1.x) + (r2.x + r3.x) + br0;
        const float Hh = (r0.y + r1.y) + (r2.y + r3.y) + br1;
        const float Cc = (r0.z + r1.z) + (r2.z + r3.z) + bc0;
        const float Ch = (r0.w + r1.w) + (r2.w + r3.w) + bc1;

        // gh = (1-sig(Ch))*Xh + (1-sig(Hh))*h ; gc = (1-sig(Hc))*Xc + (1-sig(Cc))*c
        const float Ah = one_minus_sig(Ch) * Xv.y;
        const float Sh = one_minus_sig(Hh);
        const float Ac = one_minus_sig(Hc) * Xv.x;
        const float Sc = one_minus_sig(Cc);

        h4.x = tanh_fast(fmaf(Sh, h4.x, Ah));
        h4.y = tanh_fast(fmaf(Sh, h4.y, Ah));
        h4.z = tanh_fast(fmaf(Sh, h4.z, Ah));
        h4.w = tanh_fast(fmaf(Sh, h4.w, Ah));
        h2.x = tanh_fast(fmaf(Sh, h2.x, Ah));
        h2.y = tanh_fast(fmaf(Sh, h2.y, Ah));

        c4.x = tanh_fast(fmaf(Sc, c4.x, Ac));
        c4.y = tanh_fast(fmaf(Sc, c4.y, Ac));
        c4.z = tanh_fast(fmaf(Sc, c4.z, Ac));
        c4.w = tanh_fast(fmaf(Sc, c4.w, Ac));
        c2.x = tanh_fast(fmaf(Sc, c2.x, Ac));
        c2.y = tanh_fast(fmaf(Sc, c2.y, Ac));

        // outs[t, b, :] = ht — nontemporal fire-and-forget (never drained
        // inside the loop; the lgkm-only barrier does not wait on vmcnt)
        vf4 hv4; hv4.x = h4.x; hv4.y = h4.y; hv4.z = h4.z; hv4.w = h4.w;
        vf2 hv2; hv2.x = h2.x; hv2.y = h2.y;
        __builtin_nontemporal_store(hv4, (vf4*)op + tid);
        __builtin_nontemporal_store(hv2, (vf2*)(op + 1024) + tid);
        op += OSTRIDE;
        Xv = Xnext;
        // Double-buffer safety with ONE barrier/step: a wave re-writes buf
        // (step t+2) only after barrier t+1, which every wave reaches only
        // after its step-t read of this buffer.
    };

#pragma unroll 1
    for (int t = 0; t < T_STEPS; t += 2) {
        step(red[0], t);
        step(red[1], t + 1);
    }

    {
        vf4 hv4; hv4.x = h4.x; hv4.y = h4.y; hv4.z = h4.z; hv4.w = h4.w;
        vf2 hv2; hv2.x = h2.x; hv2.y = h2.y;
        vf4 cv4; cv4.x = c4.x; cv4.y = c4.y; cv4.z = c4.z; cv4.w = c4.w;
        vf2 cv2; cv2.x = c2.x; cv2.y = c2.y;
        float* hp = hT + (size_t)b * FEAT;
        __builtin_nontemporal_store(hv4, (vf4*)hp + tid);
        __builtin_nontemporal_store(hv2, (vf2*)(hp + 1024) + tid);
        float* cp = cT + (size_t)b * FEAT;
        __builtin_nontemporal_store(cv4, (vf4*)cp + tid);
        __builtin_nontemporal_store(cv2, (vf2*)(cp + 1024) + tid);
    }
}

extern "C" void kernel_launch(void* const* d_in, const int* in_sizes, int n_in,
                              void* d_out, int out_size, void* d_ws, size_t ws_size,
                              hipStream_t stream) {
    const float* inputs = (const float*)d_in[0];
    const float* h0     = (const float*)d_in[1];
    const float* c0     = (const float*)d_in[2];
    const float* Wr     = (const float*)d_in[3];
    const float* br     = (const float*)d_in[4];
    const float* Wc     = (const float*)d_in[5];
    const float* bc     = (const float*)d_in[6];
    const float* Wi     = (const float*)d_in[7];
    const float* bi     = (const float*)d_in[8];

    float* out = (float*)d_out;
    float* X   = (float*)d_ws;               // 256 KiB: (B, T) float2

    float* outs = out;                                        // (T,B,1536)
    float* hT   = out + (size_t)NPAIRS * FEAT;                // (B,1536)
    float* cT   = hT + (size_t)BATCH * FEAT;                  // (B,1536)

    xdot_kernel<<<NPAIRS, 256, 0, stream>>>(inputs, Wi, bi, X);
    scan_kernel<<<BATCH, 256, 0, stream>>>(h0, c0, Wr, br, Wc, bc, X,
                                           outs, hT, cT);
}